// Round 4
// baseline (404.008 us; speedup 1.0000x reference)
//
#include <hip/hip_runtime.h>
#include <stdint.h>

// out[(b,m),n] = (sum_k x_q[(b,m),k] * w[n,k]) * sx[(b,m)] * ws[n] + bias[n]
// pass 1: int32 -> packed int8 (single grid-stride kernel, both tensors)
// pass 2: 256x256-tile i8 MFMA GEMM using 32x32x32 i8 MFMA (4404 TOPS ceiling
//         vs 3944 for 16x16x64), 8 waves, 4-deep LDS ring (128 KB), counted
//         vmcnt(8) pipeline (never drains in main loop), raw s_barrier
//         (1/K-tile), setprio around MFMA clusters, 16B-chunk XOR swizzle on
//         LDS layout (pre-swizzled global source). Loop body structure is the
//         R1 (137.8 us) schedule: reads + DMA-issue + MFMA cluster, compiler
//         free to interleave (pinned prefetch variant regressed, see R2).
//         R3 was an infra failure (container acquisition); source re-audited
//         (swizzle congruences, C/D map, ring liveness) and resubmitted as-is.
#define MROWS 8192
#define K_DIM 4096
#define N_DIM 4096
#define BM 256
#define BN 256
#define BK 64                 // bytes of K per tile
#define KT (K_DIM / BK)       // 64 K-tiles
#define ABYTES (BM * BK)      // 16 KB per matrix per tile
#define TBYTES (2 * ABYTES)   // 32 KB per ring slot (A+B)

#define X_ELEMS (MROWS * K_DIM)
#define W_ELEMS (N_DIM * K_DIM)

typedef __attribute__((ext_vector_type(4)))  int   int4v;
typedef __attribute__((ext_vector_type(16))) int   int16v;
typedef __attribute__((ext_vector_type(4)))  float float4v;

#define GLOAD_LDS16(gptr, lptr)                                                   \
    __builtin_amdgcn_global_load_lds((const __attribute__((address_space(1))) void*)(gptr), \
                                     (__attribute__((address_space(3))) void*)(lptr), 16, 0, 0)

// ---- pass 1: int32 -> packed int8, grid-stride, both tensors ---------------
__device__ __forceinline__ int pack4(int4v v) {
    return (int)((unsigned)(v[0] & 0xFF)
               | ((unsigned)(v[1] & 0xFF) << 8)
               | ((unsigned)(v[2] & 0xFF) << 16)
               | ((unsigned)(v[3] & 0xFF) << 24));
}

__global__ __launch_bounds__(256) void pack_i32_to_i8(
    const int4v* __restrict__ srcX, int* __restrict__ dstX, int n4x,
    const int4v* __restrict__ srcW, int* __restrict__ dstW, int n4w)
{
    const int stride = gridDim.x * blockDim.x;
    const int n4 = n4x + n4w;
    for (int i = blockIdx.x * blockDim.x + threadIdx.x; i < n4; i += stride) {
        if (i < n4x) dstX[i] = pack4(srcX[i]);
        else         dstW[i - n4x] = pack4(srcW[i - n4x]);
    }
}

// ---- pass 2: i8 GEMM + dequant epilogue -------------------------------------
// LDS swizzle (per 64B row, 4 x 16B chunks): chunk c of row r stored at slot
// (c + (r>>1)) & 3, realized by pre-swizzling the per-lane GLOBAL source so
// the hardware's linear lane*16 LDS placement lands the permutation.
// 32x32x32 A/B operand: lane l holds 16 consecutive k-bytes of row (l&31),
// chunk index c = 2*kslice + (l>>5); stored slot = (c + (row>>1)) & 3 with
// (row>>1)&3 == ((l&31)>>1)&3 (row bases are multiples of 32).
__global__ __launch_bounds__(512, 2) void i8gemm_dq_kernel(
    const int8_t* __restrict__ xq,   // (8192, 4096) packed i8
    const float*  __restrict__ sx,   // (8192,)
    const int8_t* __restrict__ wt,   // (4096, 4096) packed i8 (row = n)
    const float*  __restrict__ ws,   // (4096,)
    const float*  __restrict__ bias, // (4096,)
    float*        __restrict__ out)  // (8192, 4096) f32
{
    __shared__ __align__(16) int8_t lds8[4 * TBYTES];   // 128 KB ring

    const int tid  = threadIdx.x;
    const int wave = tid >> 6;
    const int lane = tid & 63;
    const int wr   = wave >> 2;   // 0..1 : 128-row half of the 256-row tile
    const int wcn  = wave & 3;    // 0..3 : 64-col quarter of the 256-col tile

    // XCD-aware swizzle: 512 blocks, 8 XCDs, 64 contiguous wgs per XCD
    const int bid = blockIdx.x;
    const int wg  = (bid & 7) * 64 + (bid >> 3);
    const int ct  = wg & 15;          // 16 col tiles
    const int rt  = wg >> 4;          // 32 row tiles

    // ---- staging addressing: lane covers (row = wave*16 + lane>>2, chunk = lane&3)
    // global chunk fetched = (slot - (row>>1)) & 3; (row>>1)&3 == (lane>>3)&3.
    const int srow = wave * 16 + (lane >> 2);
    const int scol = (((lane & 3) - ((lane >> 3) & 3)) & 3) * 16;
    const int8_t* gA0 = xq + (size_t)(rt * BM + srow) * K_DIM + scol;       // rows 0..127
    const int8_t* gA1 = gA0 + (size_t)128 * K_DIM;                          // rows 128..255
    const int8_t* gB0 = wt + (size_t)(ct * BN + srow) * K_DIM + scol;
    const int8_t* gB1 = gB0 + (size_t)128 * K_DIM;
    const int dA0 = wave * 1024;            // LDS dest offsets (wave-uniform)
    const int dA1 = 8192 + wave * 1024;
    const int dB0 = ABYTES + wave * 1024;
    const int dB1 = ABYTES + 8192 + wave * 1024;

    // ---- fragment read addressing (32x32 operand, same XOR swizzle) ----
    const int m32 = lane & 31;
    const int hi  = lane >> 5;
    // slot for kslice 0 = (hi + (row>>1)) & 3 ; kslice 1 = slot XOR 2 (byte XOR 32)
    const int askew = ((hi + (m32 >> 1)) & 3) * 16;
    const int aoff  = (wr * 128 + m32) * BK;            // + i*2048, + (askew ^ s*32)
    const int boff  = ABYTES + (wcn * 64 + m32) * BK;   // + j*2048, + (askew ^ s*32)

    int16v acc[4][2] = {};   // 4x2 of 32x32 int32 accumulators per wave

    // prologue: stage tiles 0..2 into slots 0..2 -> 12 loads/wave in flight
    #pragma unroll
    for (int u = 0; u < 3; ++u) {
        const size_t ko = (size_t)u * BK;
        int8_t* bb = lds8 + u * TBYTES;
        GLOAD_LDS16(gA0 + ko, bb + dA0);
        GLOAD_LDS16(gA1 + ko, bb + dA1);
        GLOAD_LDS16(gB0 + ko, bb + dB0);
        GLOAD_LDS16(gB1 + ko, bb + dB1);
    }

    #pragma unroll 4
    for (int t = 0; t < KT; ++t) {
        const int  buf = t & 3;
        const int  nb  = (t + 3) & 3;           // ring slot last read at t-1: dead
        const int  u   = (t + 3) & (KT - 1);    // wraps at the tail (data unused)
        const size_t ko = (size_t)u * BK;
        const int8_t* base = lds8 + buf * TBYTES;
        int8_t* nbb = lds8 + nb * TBYTES;

        // land this tile's 4 loads (oldest), keep 8 in flight; then barrier so
        // every wave's staging of this tile is visible to every other wave.
        asm volatile("s_waitcnt vmcnt(8)" ::: "memory");
        __builtin_amdgcn_s_barrier();
        __builtin_amdgcn_sched_barrier(0);

        // phase 0: m-tiles 0,1 (rows wr*128 + 0..63), both k-slices
        int4v a0[2][2], bf[2][2];
        #pragma unroll
        for (int i = 0; i < 2; ++i)
            #pragma unroll
            for (int s = 0; s < 2; ++s)
                a0[i][s] = *(const int4v*)(base + aoff + i * 2048 + (askew ^ (s << 5)));
        #pragma unroll
        for (int j = 0; j < 2; ++j)
            #pragma unroll
            for (int s = 0; s < 2; ++s)
                bf[j][s] = *(const int4v*)(base + boff + j * 2048 + (askew ^ (s << 5)));
        GLOAD_LDS16(gA0 + ko, nbb + dA0);   // prefetch A of tile t+3
        GLOAD_LDS16(gA1 + ko, nbb + dA1);

        __builtin_amdgcn_s_setprio(1);
        #pragma unroll
        for (int s = 0; s < 2; ++s)
            #pragma unroll
            for (int i = 0; i < 2; ++i)
                #pragma unroll
                for (int j = 0; j < 2; ++j)
                    acc[i][j] = __builtin_amdgcn_mfma_i32_32x32x32_i8(
                                    a0[i][s], bf[j][s], acc[i][j], 0, 0, 0);
        __builtin_amdgcn_s_setprio(0);

        // phase 1: m-tiles 2,3 (rows wr*128 + 64..127), B frags reused
        int4v a1[2][2];
        #pragma unroll
        for (int i = 0; i < 2; ++i)
            #pragma unroll
            for (int s = 0; s < 2; ++s)
                a1[i][s] = *(const int4v*)(base + aoff + (2 + i) * 2048 + (askew ^ (s << 5)));
        GLOAD_LDS16(gB0 + ko, nbb + dB0);   // prefetch B of tile t+3
        GLOAD_LDS16(gB1 + ko, nbb + dB1);

        __builtin_amdgcn_s_setprio(1);
        #pragma unroll
        for (int s = 0; s < 2; ++s)
            #pragma unroll
            for (int i = 0; i < 2; ++i)
                #pragma unroll
                for (int j = 0; j < 2; ++j)
                    acc[2 + i][j] = __builtin_amdgcn_mfma_i32_32x32x32_i8(
                                        a1[i][s], bf[j][s], acc[2 + i][j], 0, 0, 0);
        __builtin_amdgcn_s_setprio(0);
    }

    // drain LDS-DMA before workgroup can end (ring slots die with the WG)
    asm volatile("s_waitcnt vmcnt(0)" ::: "memory");

    // ---- epilogue: 32x32 C/D layout col=lane&31, row=(reg&3)+8*(reg>>2)+4*hi
    const int row_base = rt * BM + wr * 128;
    const int col_base = ct * BN + wcn * 64;

    float wsc[2], bsc[2];
    #pragma unroll
    for (int j = 0; j < 2; ++j) {
        const int c = col_base + j * 32 + m32;
        wsc[j] = ws[c];
        bsc[j] = bias[c];
    }

    #pragma unroll
    for (int i = 0; i < 4; ++i) {
        #pragma unroll
        for (int q = 0; q < 4; ++q) {          // register quad -> 4 consecutive rows
            const int r0 = row_base + i * 32 + q * 8 + hi * 4;
            const float4v sx4 = *(const float4v*)(sx + r0);
            #pragma unroll
            for (int j = 0; j < 2; ++j) {
                const int c = col_base + j * 32 + m32;
                float* o = out + (size_t)r0 * N_DIM + c;
                #pragma unroll
                for (int r = 0; r < 4; ++r)
                    o[(size_t)r * N_DIM] = (float)acc[i][j][q * 4 + r] * sx4[r] * wsc[j] + bsc[j];
            }
        }
    }
}

extern "C" void kernel_launch(void* const* d_in, const int* in_sizes, int n_in,
                              void* d_out, int out_size, void* d_ws, size_t ws_size,
                              hipStream_t stream) {
    const int*   xq32 = (const int*)d_in[0];
    const float* sx   = (const float*)d_in[1];
    const int*   wt32 = (const int*)d_in[2];
    const float* ws   = (const float*)d_in[3];
    const float* bias = (const float*)d_in[4];
    float* out = (float*)d_out;

    int8_t* xq8 = (int8_t*)d_ws;
    int8_t* wt8 = xq8 + (size_t)X_ELEMS;

    {
        int n4x = X_ELEMS / 4;
        int n4w = W_ELEMS / 4;
        pack_i32_to_i8<<<2048, 256, 0, stream>>>((const int4v*)xq32, (int*)xq8, n4x,
                                                 (const int4v*)wt32, (int*)wt8, n4w);
    }

    dim3 grid((MROWS / BM) * (N_DIM / BN));  // 512 blocks
    i8gemm_dq_kernel<<<grid, 512, 0, stream>>>(xq8, sx, wt8, ws, bias, out);
}